// Round 13
// baseline (617.614 us; speedup 1.0000x reference)
//
#include <hip/hip_runtime.h>
#include <math.h>

// Problem constants (DeformConv_68109591380935) — ALL TENSORS FLOAT32
#define BN_    4
#define CHI_   256
#define CHO_   256
#define HH_    96
#define WW_    96
#define HW_    (HH_*WW_)        // 9216
#define KK_    9
#define CK_    (CHI_*KK_)       // 2304
#define NRED_  (BN_*HW_)        // 36864 samples per BN channel
#define BN_EPS_ 1e-5f

// R13: deform_fused KC 64->32, LDS 40.4KB -> 24.2KB (6 blocks/CU, all 1152
// co-resident, no tail). Pitch-36-short (72B) rows replace XOR swizzle
// (R0-proven conflict-free class). All other kernels = R12-measured.

#define AP_ 36                  // LDS pitch in shorts (72B rows)

typedef short short8 __attribute__((ext_vector_type(8)));
typedef float f32x4  __attribute__((ext_vector_type(4)));

// round-to-nearest-even f32 -> bf16 bit pattern
__device__ __forceinline__ unsigned short f2bf(float v) {
    union { float f; unsigned u; } c; c.f = v;
    unsigned lsb = (c.u >> 16) & 1u;
    c.u += 0x7fffu + lsb;
    return (unsigned short)(c.u >> 16);
}

// ---------------------------------------------------------------------------
// Kernel 0a: w_conv f32 -> bf16 with K-dim permutation (c,k) -> (k,c).
// ---------------------------------------------------------------------------
__global__ __launch_bounds__(256) void w2b_perm(
    const float* __restrict__ w, unsigned short* __restrict__ wb)
{
    int idx = blockIdx.x * 256 + threadIdx.x;     // o*2304 + k*256 + c
    int o  = idx / CK_;
    int kk = idx - o * CK_;
    int k  = kk >> 8;
    int c  = kk & 255;
    wb[idx] = f2bf(w[o * CK_ + c * KK_ + k]);
}

// ---------------------------------------------------------------------------
// Kernel 0b: w_offset f32 -> bf16, kk-major permutation (27 rows).
// ---------------------------------------------------------------------------
__global__ __launch_bounds__(256) void w2b_perm27(
    const float* __restrict__ w, unsigned short* __restrict__ wb)
{
    int idx = blockIdx.x * 256 + threadIdx.x;     // < 27*2304 = 62208
    int o  = idx / CK_;
    int kk = idx - o * CK_;
    int k  = kk >> 8;
    int c  = kk & 255;
    wb[idx] = f2bf(w[o * CK_ + c * KK_ + k]);
}

// ---------------------------------------------------------------------------
// Kernel 0c: NCHW -> NHWC transpose of x.  xt[b][p][c] = x[b][c][p]
// ---------------------------------------------------------------------------
__global__ __launch_bounds__(256) void transpose_x(
    const float* __restrict__ x, float* __restrict__ xt)
{
    __shared__ float tile[64][65];
    const int t = threadIdx.x;
    const int bid = blockIdx.x;
    const int b  = bid / (144 * 4);
    const int r  = bid - b * 576;
    const int pt = r >> 2, ct = r & 3;
    const int p0 = pt * 64, c0 = ct * 64;

    const int px = t & 63, g = t >> 6;
#pragma unroll
    for (int i = 0; i < 16; i++) {
        int cr = g + i * 4;
        tile[cr][px] = x[((size_t)b * CHI_ + c0 + cr) * HW_ + p0 + px];
    }
    __syncthreads();
    const int c = t & 63;
#pragma unroll
    for (int i = 0; i < 16; i++) {
        int pr = g + i * 4;
        xt[((size_t)b * HW_ + p0 + pr) * CHI_ + c0 + c] = tile[c][pr];
    }
}

// ---------------------------------------------------------------------------
// Kernel 1: offset conv as channels-last MFMA GEMM (UNCHANGED from R12).
// ---------------------------------------------------------------------------
__global__ __launch_bounds__(256) void offset_nhwc(
    const float* __restrict__ xt, const unsigned short* __restrict__ wob,
    const float* __restrict__ bo, float* __restrict__ om)
{
    __shared__ __align__(16) unsigned short sW[32 * 64];   // 4096 B (swizzled)
    __shared__ __align__(16) unsigned short sB[64 * 64];   // 8192 B (swizzled)

    const int t = threadIdx.x;
    const int bid = blockIdx.x;
    const int u   = (bid & 7) * 72 + (bid >> 3);     // [0,576)
    const int pixtile = u % 144;
    const int b       = u / 144;
    const int p0 = pixtile * 64;

    const int lane = t & 63, wave = t >> 6;
    const int quad = lane >> 4, l15 = lane & 15;
    const int pxl  = t >> 2;           // B-stage: pixel 0..63
    const int cg   = t & 3;            // B-stage: 16-ch group
    const int aro  = t >> 3;           // A-stage: oc row 0..31
    const int ako  = t & 7;            // A-stage: 8-k group

    f32x4 acc[2];
    acc[0] = (f32x4){0.f,0.f,0.f,0.f};
    acc[1] = (f32x4){0.f,0.f,0.f,0.f};

    const float* xtb = xt + (size_t)b * HW_ * CHI_;
    char* sWb = (char*)sW;
    char* sBb = (char*)sB;

    // pixel coords for B-stage role (constant over chunks)
    const int p = p0 + pxl;
    const int h = p / WW_, w = p % WW_;

    for (int kc = 0; kc < 36; kc++) {
        if (kc) __syncthreads();
        // ---- stage A (Woff'): 32 oc x 64 kk, 1 uint4/thread, rows>=27 zero
        {
            uint4 v = make_uint4(0u, 0u, 0u, 0u);
            if (aro < 27)
                v = *reinterpret_cast<const uint4*>(
                    wob + (size_t)aro * CK_ + kc * 64 + ako * 8);
            *reinterpret_cast<uint4*>(
                sWb + (aro << 7) + ((ako << 4) ^ ((aro & 7) << 4))) = v;
        }
        // ---- stage B: 64 px x 64 ch shifted-row load (coalesced) ----
        {
            const int k  = kc >> 2;
            const int c0 = (kc & 3) << 6;
            const int yy = h + k / 3 - 1;
            const int xx = w + (k % 3) - 1;
            const bool ok = ((unsigned)yy < HH_) & ((unsigned)xx < WW_);
            union { unsigned short s[16]; uint4 q[2]; } pk;
            if (ok) {
                const float4* src = reinterpret_cast<const float4*>(
                    xtb + (size_t)(yy * WW_ + xx) * CHI_ + c0 + cg * 16);
#pragma unroll
                for (int i = 0; i < 4; i++) {
                    float4 f = src[i];
                    pk.s[i * 4 + 0] = f2bf(f.x);
                    pk.s[i * 4 + 1] = f2bf(f.y);
                    pk.s[i * 4 + 2] = f2bf(f.z);
                    pk.s[i * 4 + 3] = f2bf(f.w);
                }
            } else {
                pk.q[0] = make_uint4(0u, 0u, 0u, 0u);
                pk.q[1] = make_uint4(0u, 0u, 0u, 0u);
            }
            const int u0 = cg << 1;
            *reinterpret_cast<uint4*>(
                sBb + (pxl << 7) + ((u0 << 4) ^ ((pxl & 7) << 4))) = pk.q[0];
            *reinterpret_cast<uint4*>(
                sBb + (pxl << 7) + (((u0 + 1) << 4) ^ ((pxl & 7) << 4))) = pk.q[1];
        }
        __syncthreads();
        // ---- MFMA: 2 K-steps; A = 2 oc-tiles, B = wave's pixel quarter ----
#pragma unroll
        for (int ks = 0; ks < 2; ks++) {
            short8 a0, a1, b0;
            {
                int r = l15;
                a0 = *reinterpret_cast<const short8*>(
                    sWb + (r << 7) + (((ks << 6) + (quad << 4)) ^ ((r & 7) << 4)));
                r = 16 + l15;
                a1 = *reinterpret_cast<const short8*>(
                    sWb + (r << 7) + (((ks << 6) + (quad << 4)) ^ ((r & 7) << 4)));
                r = wave * 16 + l15;
                b0 = *reinterpret_cast<const short8*>(
                    sBb + (r << 7) + (((ks << 6) + (quad << 4)) ^ ((r & 7) << 4)));
            }
            acc[0] = __builtin_amdgcn_mfma_f32_16x16x32_bf16(a0, b0, acc[0], 0, 0, 0);
            acc[1] = __builtin_amdgcn_mfma_f32_16x16x32_bf16(a1, b0, acc[1], 0, 0, 0);
        }
    }

    // epilogue: C/D layout col=lane&15 (pixel), row=quad*4+r (oc)
#pragma unroll
    for (int mt = 0; mt < 2; mt++) {
#pragma unroll
        for (int r = 0; r < 4; r++) {
            int oc = mt * 16 + quad * 4 + r;
            if (oc < 27) {
                int pix = p0 + wave * 16 + l15;
                om[((size_t)b * 27 + oc) * HW_ + pix] = acc[mt][r] + bo[oc];
            }
        }
    }
}

// ---------------------------------------------------------------------------
// Kernel 2: fused channels-last gather + bf16 MFMA GEMM.
//   R13: KC=32 (chunk = tap kc>>3, 32 ch c0=(kc&7)*32), 72 chunks.
//   LDS pitch-36 rows (72B, conflict-free, no XOR). 24.2KB -> 6 blocks/CU.
// ---------------------------------------------------------------------------
__global__ __launch_bounds__(256, 4) void deform_fused(
    const float* __restrict__ xt, const float* __restrict__ om,
    const unsigned short* __restrict__ wb, const float* __restrict__ bconv,
    float* __restrict__ outb)
{
    __shared__ __align__(16) unsigned short sA[CHO_ * AP_]; // 18432 B
    __shared__ __align__(16) unsigned short sB[32 * AP_];   //  2304 B
    __shared__ float s_py[KK_ * 32], s_px[KK_ * 32], s_mask[KK_ * 32]; // 3456 B

    const int t = threadIdx.x;
    const int bid = blockIdx.x;
    const int u   = (bid & 7) * 144 + (bid >> 3);    // [0,1152)
    const int pixtile = u % 288;
    const int b       = u / 288;
    const int p0 = pixtile * 32;

    // ---- meta: py/px/mask for 9 taps x 32 pixels ----
    for (int e = t; e < KK_ * 32; e += 256) {
        int k = e >> 5, i = e & 31;
        int p = p0 + i;
        int h = p / WW_, w = p % WW_;
        const float* omb = om + ((size_t)b * 27) * HW_ + p;
        float dy = omb[(2 * k) * HW_];
        float dx = omb[(2 * k + 1) * HW_];
        float m  = omb[(18 + k) * HW_];
        s_py[e]   = dy + (float)(h + k / 3 - 1);
        s_px[e]   = dx + (float)(w + (k % 3) - 1);
        s_mask[e] = 1.f / (1.f + __expf(-m));
    }

    const int lane = t & 63, wave = t >> 6;
    const int quad = lane >> 4, l15 = lane & 15;
    const int pxl  = t >> 3;           // gather role: pixel 0..31
    const int cg   = t & 7;            // gather role: 4-ch group (8 groups)

    f32x4 acc[4][2];
#pragma unroll
    for (int m = 0; m < 4; m++)
#pragma unroll
        for (int n = 0; n < 2; n++)
            acc[m][n] = (f32x4){0.f, 0.f, 0.f, 0.f};

    const float* xtb = xt + (size_t)b * HW_ * CHI_;
    char* sAb = (char*)sA;
    char* sBb = (char*)sB;

    __syncthreads();   // meta visible

    for (int kc = 0; kc < 72; kc++) {              // KC=32 chunks
        const int j0 = kc * 32;
        if (kc) __syncthreads();
        // ---- stage A (W'): 256 oc x 32 kk, 4 x uint4/thread, pitch-36 ----
#pragma unroll
        for (int n = 0; n < 4; n++) {
            int e = t + n * 256;                   // < 1024
            int ocl = e >> 2, ko = e & 3;
            uint4 v = *reinterpret_cast<const uint4*>(
                wb + (size_t)ocl * CK_ + j0 + ko * 8);
            *reinterpret_cast<uint4*>(sAb + ocl * 72 + ko * 16) = v;
        }
        // ---- stage B: gather 32 px x 32 ch for tap k (coalesced) ----
        {
            const int k  = kc >> 3;
            const int c0 = (kc & 7) << 5;
            const int e  = k * 32 + pxl;
            float py = s_py[e], pxx = s_px[e], msk = s_mask[e];
            float y0f = floorf(py), x0f = floorf(pxx);
            float ly = py - y0f, lx = pxx - x0f;
            int y0 = (int)y0f, x0 = (int)x0f;
            float vy0 = ((unsigned)y0       < HH_) ? 1.f : 0.f;
            float vy1 = ((unsigned)(y0 + 1) < HH_) ? 1.f : 0.f;
            float vx0 = ((unsigned)x0       < WW_) ? 1.f : 0.f;
            float vx1 = ((unsigned)(x0 + 1) < WW_) ? 1.f : 0.f;
            int yc0 = min(max(y0, 0), HH_ - 1), yc1 = min(max(y0 + 1, 0), HH_ - 1);
            int xc0 = min(max(x0, 0), WW_ - 1), xc1 = min(max(x0 + 1, 0), WW_ - 1);
            float wy0 = 1.f - ly, wx0 = 1.f - lx;
            float w00 = wy0 * wx0 * vy0 * vx0 * msk;
            float w01 = wy0 * lx  * vy0 * vx1 * msk;
            float w10 = ly  * wx0 * vy1 * vx0 * msk;
            float w11 = ly  * lx  * vy1 * vx1 * msk;
            const float* base = xtb + c0 + cg * 4;
            float4 fa = *reinterpret_cast<const float4*>(
                base + (size_t)(yc0 * WW_ + xc0) * CHI_);
            float4 fb = *reinterpret_cast<const float4*>(
                base + (size_t)(yc0 * WW_ + xc1) * CHI_);
            float4 fc = *reinterpret_cast<const float4*>(
                base + (size_t)(yc1 * WW_ + xc0) * CHI_);
            float4 fd = *reinterpret_cast<const float4*>(
                base + (size_t)(yc1 * WW_ + xc1) * CHI_);
            union { unsigned short s[4]; uint2 q; } pk;
            pk.s[0] = f2bf(fa.x * w00 + fb.x * w01 + fc.x * w10 + fd.x * w11);
            pk.s[1] = f2bf(fa.y * w00 + fb.y * w01 + fc.y * w10 + fd.y * w11);
            pk.s[2] = f2bf(fa.z * w00 + fb.z * w01 + fc.z * w10 + fd.z * w11);
            pk.s[3] = f2bf(fa.w * w00 + fb.w * w01 + fc.w * w10 + fd.w * w11);
            *reinterpret_cast<uint2*>(sBb + pxl * 72 + cg * 8) = pk.q;
        }
        __syncthreads();
        // ---- MFMA: single K-step of 32; wave = 64-oc slice, 32 px ----
        {
            short8 afr[4], bfr[2];
#pragma unroll
            for (int m = 0; m < 4; m++) {
                int r = wave * 64 + m * 16 + l15;
                afr[m] = *reinterpret_cast<const short8*>(sAb + r * 72 + quad * 16);
            }
#pragma unroll
            for (int n = 0; n < 2; n++) {
                int r = n * 16 + l15;
                bfr[n] = *reinterpret_cast<const short8*>(sBb + r * 72 + quad * 16);
            }
#pragma unroll
            for (int m = 0; m < 4; m++)
#pragma unroll
                for (int n = 0; n < 2; n++)
                    acc[m][n] = __builtin_amdgcn_mfma_f32_16x16x32_bf16(
                        afr[m], bfr[n], acc[m][n], 0, 0, 0);
        }
    }

    // ---- epilogue: C/D layout col=lane&15 (pixel), row=quad*4+r (oc) ----
#pragma unroll
    for (int m = 0; m < 4; m++) {
#pragma unroll
        for (int n = 0; n < 2; n++) {
#pragma unroll
            for (int r = 0; r < 4; r++) {
                int oc  = wave * 64 + m * 16 + quad * 4 + r;
                int pix = p0 + n * 16 + l15;
                outb[((size_t)b * CHO_ + oc) * HW_ + pix] = acc[m][n][r] + bconv[oc];
            }
        }
    }
}

// ---------------------------------------------------------------------------
// Kernel 3a: BN partial stats. 2048 blocks = channel x 8 slices, float4 loads.
// ---------------------------------------------------------------------------
__global__ __launch_bounds__(256) void bn_stats_part(
    const float* __restrict__ outb, float* __restrict__ part)
{
    const int bid = blockIdx.x;            // 2048
    const int o = bid >> 3, sl = bid & 7;
    const int t = threadIdx.x;
    float s = 0.f, s2 = 0.f;
    for (int b = 0; b < BN_; b++) {
        const float4* base = reinterpret_cast<const float4*>(
            outb + ((size_t)b * CHO_ + o) * HW_ + sl * 1152);
        for (int i = t; i < 288; i += 256) {     // 288 float4 = 1152 floats
            float4 v = base[i];
            s  += v.x + v.y + v.z + v.w;
            s2 += v.x * v.x + v.y * v.y + v.z * v.z + v.w * v.w;
        }
    }
#pragma unroll
    for (int off = 32; off > 0; off >>= 1) {
        s  += __shfl_down(s,  off, 64);
        s2 += __shfl_down(s2, off, 64);
    }
    __shared__ float rs[4], rs2[4];
    int lane = t & 63, wv = t >> 6;
    if (lane == 0) { rs[wv] = s; rs2[wv] = s2; }
    __syncthreads();
    if (t == 0) {
        part[o * 8 + sl]                = rs[0] + rs[1] + rs[2] + rs[3];
        part[CHO_ * 8 + o * 8 + sl]     = rs2[0] + rs2[1] + rs2[2] + rs2[3];
    }
}

// ---------------------------------------------------------------------------
// Kernel 3b: deterministic reduce of 8 partials per channel.
// ---------------------------------------------------------------------------
__global__ __launch_bounds__(256) void bn_reduce(
    const float* __restrict__ part, float* __restrict__ stats)
{
    int o = threadIdx.x;                   // one block of 256
    float s = 0.f, s2 = 0.f;
#pragma unroll
    for (int i = 0; i < 8; i++) {
        s  += part[o * 8 + i];
        s2 += part[CHO_ * 8 + o * 8 + i];
    }
    stats[o]        = s;
    stats[CHO_ + o] = s2;
}

// ---------------------------------------------------------------------------
// Kernel 4: BN apply + ReLU, f32 out
// ---------------------------------------------------------------------------
__global__ __launch_bounds__(256) void bn_apply(
    const float* __restrict__ outb, const float* __restrict__ stats,
    const float* __restrict__ gamma, const float* __restrict__ beta,
    float* __restrict__ y)
{
    int idx = blockIdx.x * 256 + threadIdx.x;
    size_t i0 = (size_t)idx * 4;                  // < 9437184
    int o = (int)((i0 / HW_) % CHO_);
    float4 v = *reinterpret_cast<const float4*>(outb + i0);
    const float invN = 1.f / (float)NRED_;
    float mu  = stats[o] * invN;
    float var = stats[CHO_ + o] * invN - mu * mu;
    float inv = rsqrtf(var + BN_EPS_);
    float sc = gamma[o] * inv;
    float sh = beta[o] - mu * sc;
    float4 r;
    r.x = fmaxf(v.x * sc + sh, 0.f);
    r.y = fmaxf(v.y * sc + sh, 0.f);
    r.z = fmaxf(v.z * sc + sh, 0.f);
    r.w = fmaxf(v.w * sc + sh, 0.f);
    *reinterpret_cast<float4*>(y + i0) = r;
}

// ---------------------------------------------------------------------------
extern "C" void kernel_launch(void* const* d_in, const int* in_sizes, int n_in,
                              void* d_out, int out_size, void* d_ws, size_t ws_size,
                              hipStream_t stream)
{
    const float* x   = (const float*)d_in[0];
    const float* wof = (const float*)d_in[1];
    const float* bof = (const float*)d_in[2];
    const float* wcv = (const float*)d_in[3];
    const float* bcv = (const float*)d_in[4];
    const float* gam = (const float*)d_in[5];
    const float* bet = (const float*)d_in[6];
    float* y = (float*)d_out;

    char* ws = (char*)d_ws;
    float*          om    = (float*)ws;                                   // 3.98 MB
    float*          outb  = (float*)(ws + (size_t)4 * 1024 * 1024);       // 36 MB
    float*          stats = (float*)(ws + (size_t)40 * 1024 * 1024);      // 2 KB
    unsigned short* wbf2  = (unsigned short*)(ws + (size_t)40 * 1024 * 1024 + 8192);            // 1.125 MB
    unsigned short* wob   = (unsigned short*)(ws + (size_t)40 * 1024 * 1024 + 8192 + 1179648);  // 121.5 KB
    float*          xt    = (float*)(ws + (size_t)44 * 1024 * 1024);      // 37.75 MB
    float*          part  = (float*)(ws + (size_t)82 * 1024 * 1024);      // 16 KB

    w2b_perm<<<(CHO_ * CK_) / 256, 256, 0, stream>>>(wcv, wbf2);  // 2304 blocks
    w2b_perm27<<<(27 * CK_) / 256, 256, 0, stream>>>(wof, wob);   // 243 blocks
    transpose_x<<<BN_ * 144 * 4, 256, 0, stream>>>(x, xt);        // 2304 blocks
    offset_nhwc<<<BN_ * 144, 256, 0, stream>>>(xt, wob, bof, om); // 576 blocks
    deform_fused<<<BN_ * 2 * (HW_ / 64), 256, 0, stream>>>(xt, om, wbf2, bcv, outb);
    bn_stats_part<<<CHO_ * 8, 256, 0, stream>>>(outb, part);      // 2048 blocks
    bn_reduce<<<1, 256, 0, stream>>>(part, stats);
    bn_apply<<<(BN_ * CHO_ * HW_) / (4 * 256), 256, 0, stream>>>(outb, stats, gam, bet, y);
}

// Round 14
// 298.930 us; speedup vs baseline: 2.0661x; 2.0661x over previous
//
#include <hip/hip_runtime.h>
#include <math.h>

// Problem constants (DeformConv_68109591380935) — ALL TENSORS FLOAT32
#define BN_    4
#define CHI_   256
#define CHO_   256
#define HH_    96
#define WW_    96
#define HW_    (HH_*WW_)        // 9216
#define KK_    9
#define CK_    (CHI_*KK_)       // 2304
#define NRED_  (BN_*HW_)        // 36864 samples per BN channel
#define BN_EPS_ 1e-5f

// R14: deform_fused reverted to R12-measured form (KC=64, XOR swizzle,
// 133 us — R13's KC=32 regressed 3.5x: fixed per-chunk latency doesn't
// shrink with chunk size; pitch-36 added conflicts; VGPR sank to 44).
// bn_apply: 32-bit index math (was 64-bit div chain).

typedef short short8 __attribute__((ext_vector_type(8)));
typedef float f32x4  __attribute__((ext_vector_type(4)));

// round-to-nearest-even f32 -> bf16 bit pattern
__device__ __forceinline__ unsigned short f2bf(float v) {
    union { float f; unsigned u; } c; c.f = v;
    unsigned lsb = (c.u >> 16) & 1u;
    c.u += 0x7fffu + lsb;
    return (unsigned short)(c.u >> 16);
}

// ---------------------------------------------------------------------------
// Kernel 0a: w_conv f32 -> bf16 with K-dim permutation (c,k) -> (k,c).
// ---------------------------------------------------------------------------
__global__ __launch_bounds__(256) void w2b_perm(
    const float* __restrict__ w, unsigned short* __restrict__ wb)
{
    int idx = blockIdx.x * 256 + threadIdx.x;     // o*2304 + k*256 + c
    int o  = idx / CK_;
    int kk = idx - o * CK_;
    int k  = kk >> 8;
    int c  = kk & 255;
    wb[idx] = f2bf(w[o * CK_ + c * KK_ + k]);
}

// ---------------------------------------------------------------------------
// Kernel 0b: w_offset f32 -> bf16, kk-major permutation (27 rows).
// ---------------------------------------------------------------------------
__global__ __launch_bounds__(256) void w2b_perm27(
    const float* __restrict__ w, unsigned short* __restrict__ wb)
{
    int idx = blockIdx.x * 256 + threadIdx.x;     // < 27*2304 = 62208
    int o  = idx / CK_;
    int kk = idx - o * CK_;
    int k  = kk >> 8;
    int c  = kk & 255;
    wb[idx] = f2bf(w[o * CK_ + c * KK_ + k]);
}

// ---------------------------------------------------------------------------
// Kernel 0c: NCHW -> NHWC transpose of x.  xt[b][p][c] = x[b][c][p]
// ---------------------------------------------------------------------------
__global__ __launch_bounds__(256) void transpose_x(
    const float* __restrict__ x, float* __restrict__ xt)
{
    __shared__ float tile[64][65];
    const int t = threadIdx.x;
    const int bid = blockIdx.x;
    const int b  = bid / (144 * 4);
    const int r  = bid - b * 576;
    const int pt = r >> 2, ct = r & 3;
    const int p0 = pt * 64, c0 = ct * 64;

    const int px = t & 63, g = t >> 6;
#pragma unroll
    for (int i = 0; i < 16; i++) {
        int cr = g + i * 4;
        tile[cr][px] = x[((size_t)b * CHI_ + c0 + cr) * HW_ + p0 + px];
    }
    __syncthreads();
    const int c = t & 63;
#pragma unroll
    for (int i = 0; i < 16; i++) {
        int pr = g + i * 4;
        xt[((size_t)b * HW_ + p0 + pr) * CHI_ + c0 + c] = tile[c][pr];
    }
}

// ---------------------------------------------------------------------------
// Kernel 1: offset conv as channels-last MFMA GEMM (UNCHANGED from R12).
// ---------------------------------------------------------------------------
__global__ __launch_bounds__(256) void offset_nhwc(
    const float* __restrict__ xt, const unsigned short* __restrict__ wob,
    const float* __restrict__ bo, float* __restrict__ om)
{
    __shared__ __align__(16) unsigned short sW[32 * 64];   // 4096 B (swizzled)
    __shared__ __align__(16) unsigned short sB[64 * 64];   // 8192 B (swizzled)

    const int t = threadIdx.x;
    const int bid = blockIdx.x;
    const int u   = (bid & 7) * 72 + (bid >> 3);     // [0,576)
    const int pixtile = u % 144;
    const int b       = u / 144;
    const int p0 = pixtile * 64;

    const int lane = t & 63, wave = t >> 6;
    const int quad = lane >> 4, l15 = lane & 15;
    const int pxl  = t >> 2;           // B-stage: pixel 0..63
    const int cg   = t & 3;            // B-stage: 16-ch group
    const int aro  = t >> 3;           // A-stage: oc row 0..31
    const int ako  = t & 7;            // A-stage: 8-k group

    f32x4 acc[2];
    acc[0] = (f32x4){0.f,0.f,0.f,0.f};
    acc[1] = (f32x4){0.f,0.f,0.f,0.f};

    const float* xtb = xt + (size_t)b * HW_ * CHI_;
    char* sWb = (char*)sW;
    char* sBb = (char*)sB;

    // pixel coords for B-stage role (constant over chunks)
    const int p = p0 + pxl;
    const int h = p / WW_, w = p % WW_;

    for (int kc = 0; kc < 36; kc++) {
        if (kc) __syncthreads();
        // ---- stage A (Woff'): 32 oc x 64 kk, 1 uint4/thread, rows>=27 zero
        {
            uint4 v = make_uint4(0u, 0u, 0u, 0u);
            if (aro < 27)
                v = *reinterpret_cast<const uint4*>(
                    wob + (size_t)aro * CK_ + kc * 64 + ako * 8);
            *reinterpret_cast<uint4*>(
                sWb + (aro << 7) + ((ako << 4) ^ ((aro & 7) << 4))) = v;
        }
        // ---- stage B: 64 px x 64 ch shifted-row load (coalesced) ----
        {
            const int k  = kc >> 2;
            const int c0 = (kc & 3) << 6;
            const int yy = h + k / 3 - 1;
            const int xx = w + (k % 3) - 1;
            const bool ok = ((unsigned)yy < HH_) & ((unsigned)xx < WW_);
            union { unsigned short s[16]; uint4 q[2]; } pk;
            if (ok) {
                const float4* src = reinterpret_cast<const float4*>(
                    xtb + (size_t)(yy * WW_ + xx) * CHI_ + c0 + cg * 16);
#pragma unroll
                for (int i = 0; i < 4; i++) {
                    float4 f = src[i];
                    pk.s[i * 4 + 0] = f2bf(f.x);
                    pk.s[i * 4 + 1] = f2bf(f.y);
                    pk.s[i * 4 + 2] = f2bf(f.z);
                    pk.s[i * 4 + 3] = f2bf(f.w);
                }
            } else {
                pk.q[0] = make_uint4(0u, 0u, 0u, 0u);
                pk.q[1] = make_uint4(0u, 0u, 0u, 0u);
            }
            const int u0 = cg << 1;
            *reinterpret_cast<uint4*>(
                sBb + (pxl << 7) + ((u0 << 4) ^ ((pxl & 7) << 4))) = pk.q[0];
            *reinterpret_cast<uint4*>(
                sBb + (pxl << 7) + (((u0 + 1) << 4) ^ ((pxl & 7) << 4))) = pk.q[1];
        }
        __syncthreads();
        // ---- MFMA: 2 K-steps; A = 2 oc-tiles, B = wave's pixel quarter ----
#pragma unroll
        for (int ks = 0; ks < 2; ks++) {
            short8 a0, a1, b0;
            {
                int r = l15;
                a0 = *reinterpret_cast<const short8*>(
                    sWb + (r << 7) + (((ks << 6) + (quad << 4)) ^ ((r & 7) << 4)));
                r = 16 + l15;
                a1 = *reinterpret_cast<const short8*>(
                    sWb + (r << 7) + (((ks << 6) + (quad << 4)) ^ ((r & 7) << 4)));
                r = wave * 16 + l15;
                b0 = *reinterpret_cast<const short8*>(
                    sBb + (r << 7) + (((ks << 6) + (quad << 4)) ^ ((r & 7) << 4)));
            }
            acc[0] = __builtin_amdgcn_mfma_f32_16x16x32_bf16(a0, b0, acc[0], 0, 0, 0);
            acc[1] = __builtin_amdgcn_mfma_f32_16x16x32_bf16(a1, b0, acc[1], 0, 0, 0);
        }
    }

    // epilogue: C/D layout col=lane&15 (pixel), row=quad*4+r (oc)
#pragma unroll
    for (int mt = 0; mt < 2; mt++) {
#pragma unroll
        for (int r = 0; r < 4; r++) {
            int oc = mt * 16 + quad * 4 + r;
            if (oc < 27) {
                int pix = p0 + wave * 16 + l15;
                om[((size_t)b * 27 + oc) * HW_ + pix] = acc[mt][r] + bo[oc];
            }
        }
    }
}

// ---------------------------------------------------------------------------
// Kernel 2: fused channels-last gather + bf16 MFMA GEMM (px-split).
//   REVERTED to R12-measured form (KC=64, XOR swizzle, 133 us).
// ---------------------------------------------------------------------------
__global__ __launch_bounds__(256, 4) void deform_fused(
    const float* __restrict__ xt, const float* __restrict__ om,
    const unsigned short* __restrict__ wb, const float* __restrict__ bconv,
    float* __restrict__ outb)
{
    __shared__ __align__(16) unsigned short sA[CHO_ * 64];   // 32768 B (swizzled)
    __shared__ __align__(16) unsigned short sB[32 * 64];     //  4096 B (swizzled)
    __shared__ float s_py[KK_ * 32], s_px[KK_ * 32], s_mask[KK_ * 32]; // 3456 B

    const int t = threadIdx.x;
    const int bid = blockIdx.x;
    const int u   = (bid & 7) * 144 + (bid >> 3);    // [0,1152)
    const int pixtile = u % 288;
    const int b       = u / 288;
    const int p0 = pixtile * 32;

    for (int e = t; e < KK_ * 32; e += 256) {
        int k = e >> 5, i = e & 31;
        int p = p0 + i;
        int h = p / WW_, w = p % WW_;
        const float* omb = om + ((size_t)b * 27) * HW_ + p;
        float dy = omb[(2 * k) * HW_];
        float dx = omb[(2 * k + 1) * HW_];
        float m  = omb[(18 + k) * HW_];
        s_py[e]   = dy + (float)(h + k / 3 - 1);
        s_px[e]   = dx + (float)(w + (k % 3) - 1);
        s_mask[e] = 1.f / (1.f + __expf(-m));
    }

    const int lane = t & 63, wave = t >> 6;
    const int quad = lane >> 4, l15 = lane & 15;
    const int pxl  = t >> 3;           // gather role: pixel 0..31
    const int cg   = t & 7;            // gather role: 8-ch group

    f32x4 acc[4][2];
#pragma unroll
    for (int m = 0; m < 4; m++)
#pragma unroll
        for (int n = 0; n < 2; n++)
            acc[m][n] = (f32x4){0.f, 0.f, 0.f, 0.f};

    const float* xtb = xt + (size_t)b * HW_ * CHI_;
    char* sAb = (char*)sA;
    char* sBb = (char*)sB;

    __syncthreads();   // meta visible

    for (int kc = 0; kc < 36; kc++) {
        const int j0 = kc * 64;
        if (kc) __syncthreads();
#pragma unroll
        for (int n = 0; n < 8; n++) {
            int e = t + n * 256;                   // < 2048
            int ocl = e >> 3, ko = e & 7;
            uint4 v = *reinterpret_cast<const uint4*>(
                wb + (size_t)ocl * CK_ + j0 + ko * 8);
            *reinterpret_cast<uint4*>(
                sAb + (ocl << 7) + ((ko << 4) ^ ((ocl & 7) << 4))) = v;
        }
        {
            const int k  = kc >> 2;
            const int c0 = (kc & 3) << 6;
            const int e  = k * 32 + pxl;
            float py = s_py[e], pxx = s_px[e], msk = s_mask[e];
            float y0f = floorf(py), x0f = floorf(pxx);
            float ly = py - y0f, lx = pxx - x0f;
            int y0 = (int)y0f, x0 = (int)x0f;
            float vy0 = ((unsigned)y0       < HH_) ? 1.f : 0.f;
            float vy1 = ((unsigned)(y0 + 1) < HH_) ? 1.f : 0.f;
            float vx0 = ((unsigned)x0       < WW_) ? 1.f : 0.f;
            float vx1 = ((unsigned)(x0 + 1) < WW_) ? 1.f : 0.f;
            int yc0 = min(max(y0, 0), HH_ - 1), yc1 = min(max(y0 + 1, 0), HH_ - 1);
            int xc0 = min(max(x0, 0), WW_ - 1), xc1 = min(max(x0 + 1, 0), WW_ - 1);
            float wy0 = 1.f - ly, wx0 = 1.f - lx;
            float w00 = wy0 * wx0 * vy0 * vx0 * msk;
            float w01 = wy0 * lx  * vy0 * vx1 * msk;
            float w10 = ly  * wx0 * vy1 * vx0 * msk;
            float w11 = ly  * lx  * vy1 * vx1 * msk;
            const float* base = xtb + c0 + cg * 8;
            const float4* r00 = reinterpret_cast<const float4*>(
                base + (size_t)(yc0 * WW_ + xc0) * CHI_);
            const float4* r01 = reinterpret_cast<const float4*>(
                base + (size_t)(yc0 * WW_ + xc1) * CHI_);
            const float4* r10 = reinterpret_cast<const float4*>(
                base + (size_t)(yc1 * WW_ + xc0) * CHI_);
            const float4* r11 = reinterpret_cast<const float4*>(
                base + (size_t)(yc1 * WW_ + xc1) * CHI_);
            union { unsigned short s[8]; uint4 q; } pk;
#pragma unroll
            for (int i = 0; i < 2; i++) {
                float4 fa = r00[i], fb = r01[i], fc = r10[i], fd = r11[i];
                pk.s[i * 4 + 0] = f2bf(fa.x * w00 + fb.x * w01 + fc.x * w10 + fd.x * w11);
                pk.s[i * 4 + 1] = f2bf(fa.y * w00 + fb.y * w01 + fc.y * w10 + fd.y * w11);
                pk.s[i * 4 + 2] = f2bf(fa.z * w00 + fb.z * w01 + fc.z * w10 + fd.z * w11);
                pk.s[i * 4 + 3] = f2bf(fa.w * w00 + fb.w * w01 + fc.w * w10 + fd.w * w11);
            }
            *reinterpret_cast<uint4*>(
                sBb + (pxl << 7) + ((cg << 4) ^ ((pxl & 7) << 4))) = pk.q;
        }
        __syncthreads();
#pragma unroll
        for (int ks = 0; ks < 2; ks++) {
            short8 afr[4], bfr[2];
#pragma unroll
            for (int m = 0; m < 4; m++) {
                int r = wave * 64 + m * 16 + l15;
                afr[m] = *reinterpret_cast<const short8*>(
                    sAb + (r << 7) + (((ks << 6) + (quad << 4)) ^ ((r & 7) << 4)));
            }
#pragma unroll
            for (int n = 0; n < 2; n++) {
                int r = n * 16 + l15;
                bfr[n] = *reinterpret_cast<const short8*>(
                    sBb + (r << 7) + (((ks << 6) + (quad << 4)) ^ ((r & 7) << 4)));
            }
#pragma unroll
            for (int m = 0; m < 4; m++)
#pragma unroll
                for (int n = 0; n < 2; n++)
                    acc[m][n] = __builtin_amdgcn_mfma_f32_16x16x32_bf16(
                        afr[m], bfr[n], acc[m][n], 0, 0, 0);
        }
    }

#pragma unroll
    for (int m = 0; m < 4; m++) {
#pragma unroll
        for (int n = 0; n < 2; n++) {
#pragma unroll
            for (int r = 0; r < 4; r++) {
                int oc  = wave * 64 + m * 16 + quad * 4 + r;
                int pix = p0 + n * 16 + l15;
                outb[((size_t)b * CHO_ + oc) * HW_ + pix] = acc[m][n][r] + bconv[oc];
            }
        }
    }
}

// ---------------------------------------------------------------------------
// Kernel 3a: BN partial stats. 2048 blocks = channel x 8 slices, float4 loads.
// ---------------------------------------------------------------------------
__global__ __launch_bounds__(256) void bn_stats_part(
    const float* __restrict__ outb, float* __restrict__ part)
{
    const int bid = blockIdx.x;            // 2048
    const int o = bid >> 3, sl = bid & 7;
    const int t = threadIdx.x;
    float s = 0.f, s2 = 0.f;
    for (int b = 0; b < BN_; b++) {
        const float4* base = reinterpret_cast<const float4*>(
            outb + ((size_t)b * CHO_ + o) * HW_ + sl * 1152);
        for (int i = t; i < 288; i += 256) {     // 288 float4 = 1152 floats
            float4 v = base[i];
            s  += v.x + v.y + v.z + v.w;
            s2 += v.x * v.x + v.y * v.y + v.z * v.z + v.w * v.w;
        }
    }
#pragma unroll
    for (int off = 32; off > 0; off >>= 1) {
        s  += __shfl_down(s,  off, 64);
        s2 += __shfl_down(s2, off, 64);
    }
    __shared__ float rs[4], rs2[4];
    int lane = t & 63, wv = t >> 6;
    if (lane == 0) { rs[wv] = s; rs2[wv] = s2; }
    __syncthreads();
    if (t == 0) {
        part[o * 8 + sl]                = rs[0] + rs[1] + rs[2] + rs[3];
        part[CHO_ * 8 + o * 8 + sl]     = rs2[0] + rs2[1] + rs2[2] + rs2[3];
    }
}

// ---------------------------------------------------------------------------
// Kernel 3b: deterministic reduce of 8 partials per channel.
// ---------------------------------------------------------------------------
__global__ __launch_bounds__(256) void bn_reduce(
    const float* __restrict__ part, float* __restrict__ stats)
{
    int o = threadIdx.x;                   // one block of 256
    float s = 0.f, s2 = 0.f;
#pragma unroll
    for (int i = 0; i < 8; i++) {
        s  += part[o * 8 + i];
        s2 += part[CHO_ * 8 + o * 8 + i];
    }
    stats[o]        = s;
    stats[CHO_ + o] = s2;
}

// ---------------------------------------------------------------------------
// Kernel 4: BN apply + ReLU, f32 out (R14: 32-bit index math)
// ---------------------------------------------------------------------------
__global__ __launch_bounds__(256) void bn_apply(
    const float* __restrict__ outb, const float* __restrict__ stats,
    const float* __restrict__ gamma, const float* __restrict__ beta,
    float* __restrict__ y)
{
    unsigned idx = blockIdx.x * 256 + threadIdx.x;    // < 2359296
    unsigned o = (idx / 2304u) & 255u;                // (idx*4/HW_) % CHO_
    size_t i0 = (size_t)idx * 4;
    float4 v = *reinterpret_cast<const float4*>(outb + i0);
    const float invN = 1.f / (float)NRED_;
    float mu  = stats[o] * invN;
    float var = stats[CHO_ + o] * invN - mu * mu;
    float inv = rsqrtf(var + BN_EPS_);
    float sc = gamma[o] * inv;
    float sh = beta[o] - mu * sc;
    float4 r;
    r.x = fmaxf(v.x * sc + sh, 0.f);
    r.y = fmaxf(v.y * sc + sh, 0.f);
    r.z = fmaxf(v.z * sc + sh, 0.f);
    r.w = fmaxf(v.w * sc + sh, 0.f);
    *reinterpret_cast<float4*>(y + i0) = r;
}

// ---------------------------------------------------------------------------
extern "C" void kernel_launch(void* const* d_in, const int* in_sizes, int n_in,
                              void* d_out, int out_size, void* d_ws, size_t ws_size,
                              hipStream_t stream)
{
    const float* x   = (const float*)d_in[0];
    const float* wof = (const float*)d_in[1];
    const float* bof = (const float*)d_in[2];
    const float* wcv = (const float*)d_in[3];
    const float* bcv = (const float*)d_in[4];
    const float* gam = (const float*)d_in[5];
    const float* bet = (const float*)d_in[6];
    float* y = (float*)d_out;

    char* ws = (char*)d_ws;
    float*          om    = (float*)ws;                                   // 3.98 MB
    float*          outb  = (float*)(ws + (size_t)4 * 1024 * 1024);       // 36 MB
    float*          stats = (float*)(ws + (size_t)40 * 1024 * 1024);      // 2 KB
    unsigned short* wbf2  = (unsigned short*)(ws + (size_t)40 * 1024 * 1024 + 8192);            // 1.125 MB
    unsigned short* wob   = (unsigned short*)(ws + (size_t)40 * 1024 * 1024 + 8192 + 1179648);  // 121.5 KB
    float*          xt    = (float*)(ws + (size_t)44 * 1024 * 1024);      // 37.75 MB
    float*          part  = (float*)(ws + (size_t)82 * 1024 * 1024);      // 16 KB

    w2b_perm<<<(CHO_ * CK_) / 256, 256, 0, stream>>>(wcv, wbf2);  // 2304 blocks
    w2b_perm27<<<(27 * CK_) / 256, 256, 0, stream>>>(wof, wob);   // 243 blocks
    transpose_x<<<BN_ * 144 * 4, 256, 0, stream>>>(x, xt);        // 2304 blocks
    offset_nhwc<<<BN_ * 144, 256, 0, stream>>>(xt, wob, bof, om); // 576 blocks
    deform_fused<<<BN_ * 2 * (HW_ / 64), 256, 0, stream>>>(xt, om, wbf2, bcv, outb);
    bn_stats_part<<<CHO_ * 8, 256, 0, stream>>>(outb, part);      // 2048 blocks
    bn_reduce<<<1, 256, 0, stream>>>(part, stats);
    bn_apply<<<(BN_ * CHO_ * HW_) / (4 * 256), 256, 0, stream>>>(outb, stats, gam, bet, y);
}

// Round 15
// 275.230 us; speedup vs baseline: 2.2440x; 1.0861x over previous
//
#include <hip/hip_runtime.h>
#include <math.h>

// Problem constants (DeformConv_68109591380935) — ALL TENSORS FLOAT32
#define BN_    4
#define CHI_   256
#define CHO_   256
#define HH_    96
#define WW_    96
#define HW_    (HH_*WW_)        // 9216
#define KK_    9
#define CK_    (CHI_*KK_)       // 2304
#define NRED_  (BN_*HW_)        // 36864 samples per BN channel
#define BN_EPS_ 1e-5f

// R15: deform_fused A-stage via global_load_lds width=16 (inverse-swizzled
// per-lane global source keeps the XOR'd LDS image; dest linear per rule #21).
// offset_nhwc reads pre-converted bf16 NHWC (xt16, numerically identical).
// Schedule/tile/swizzle otherwise = R12/R14-measured (133 us control).

typedef short short8 __attribute__((ext_vector_type(8)));
typedef float f32x4  __attribute__((ext_vector_type(4)));

// round-to-nearest-even f32 -> bf16 bit pattern
__device__ __forceinline__ unsigned short f2bf(float v) {
    union { float f; unsigned u; } c; c.f = v;
    unsigned lsb = (c.u >> 16) & 1u;
    c.u += 0x7fffu + lsb;
    return (unsigned short)(c.u >> 16);
}

// ---------------------------------------------------------------------------
// Kernel 0a: w_conv f32 -> bf16 with K-dim permutation (c,k) -> (k,c).
// ---------------------------------------------------------------------------
__global__ __launch_bounds__(256) void w2b_perm(
    const float* __restrict__ w, unsigned short* __restrict__ wb)
{
    int idx = blockIdx.x * 256 + threadIdx.x;     // o*2304 + k*256 + c
    int o  = idx / CK_;
    int kk = idx - o * CK_;
    int k  = kk >> 8;
    int c  = kk & 255;
    wb[idx] = f2bf(w[o * CK_ + c * KK_ + k]);
}

// ---------------------------------------------------------------------------
// Kernel 0b: w_offset f32 -> bf16, kk-major permutation (27 rows).
// ---------------------------------------------------------------------------
__global__ __launch_bounds__(256) void w2b_perm27(
    const float* __restrict__ w, unsigned short* __restrict__ wb)
{
    int idx = blockIdx.x * 256 + threadIdx.x;     // < 27*2304 = 62208
    int o  = idx / CK_;
    int kk = idx - o * CK_;
    int k  = kk >> 8;
    int c  = kk & 255;
    wb[idx] = f2bf(w[o * CK_ + c * KK_ + k]);
}

// ---------------------------------------------------------------------------
// Kernel 0c: NCHW -> NHWC transpose of x.  xt[b][p][c] = x[b][c][p] (f32)
//            + xt16 (bf16 copy, for offset_nhwc — numerically identical).
// ---------------------------------------------------------------------------
__global__ __launch_bounds__(256) void transpose_x(
    const float* __restrict__ x, float* __restrict__ xt,
    unsigned short* __restrict__ xt16)
{
    __shared__ float tile[64][65];
    const int t = threadIdx.x;
    const int bid = blockIdx.x;
    const int b  = bid / (144 * 4);
    const int r  = bid - b * 576;
    const int pt = r >> 2, ct = r & 3;
    const int p0 = pt * 64, c0 = ct * 64;

    const int px = t & 63, g = t >> 6;
#pragma unroll
    for (int i = 0; i < 16; i++) {
        int cr = g + i * 4;
        tile[cr][px] = x[((size_t)b * CHI_ + c0 + cr) * HW_ + p0 + px];
    }
    __syncthreads();
    const int c = t & 63;
#pragma unroll
    for (int i = 0; i < 16; i++) {
        int pr = g + i * 4;
        float v = tile[c][pr];
        size_t o = ((size_t)b * HW_ + p0 + pr) * CHI_ + c0 + c;
        xt[o]   = v;
        xt16[o] = f2bf(v);
    }
}

// ---------------------------------------------------------------------------
// Kernel 1: offset conv as channels-last MFMA GEMM.
//   R15: B-stage reads xt16 (bf16) — half the bytes, no f2bf.
// ---------------------------------------------------------------------------
__global__ __launch_bounds__(256) void offset_nhwc(
    const unsigned short* __restrict__ xt16, const unsigned short* __restrict__ wob,
    const float* __restrict__ bo, float* __restrict__ om)
{
    __shared__ __align__(16) unsigned short sW[32 * 64];   // 4096 B (swizzled)
    __shared__ __align__(16) unsigned short sB[64 * 64];   // 8192 B (swizzled)

    const int t = threadIdx.x;
    const int bid = blockIdx.x;
    const int u   = (bid & 7) * 72 + (bid >> 3);     // [0,576)
    const int pixtile = u % 144;
    const int b       = u / 144;
    const int p0 = pixtile * 64;

    const int lane = t & 63, wave = t >> 6;
    const int quad = lane >> 4, l15 = lane & 15;
    const int pxl  = t >> 2;           // B-stage: pixel 0..63
    const int cg   = t & 3;            // B-stage: 16-ch group
    const int aro  = t >> 3;           // A-stage: oc row 0..31
    const int ako  = t & 7;            // A-stage: 8-k group

    f32x4 acc[2];
    acc[0] = (f32x4){0.f,0.f,0.f,0.f};
    acc[1] = (f32x4){0.f,0.f,0.f,0.f};

    const unsigned short* xtb = xt16 + (size_t)b * HW_ * CHI_;
    char* sWb = (char*)sW;
    char* sBb = (char*)sB;

    // pixel coords for B-stage role (constant over chunks)
    const int p = p0 + pxl;
    const int h = p / WW_, w = p % WW_;

    for (int kc = 0; kc < 36; kc++) {
        if (kc) __syncthreads();
        // ---- stage A (Woff'): 32 oc x 64 kk, 1 uint4/thread, rows>=27 zero
        {
            uint4 v = make_uint4(0u, 0u, 0u, 0u);
            if (aro < 27)
                v = *reinterpret_cast<const uint4*>(
                    wob + (size_t)aro * CK_ + kc * 64 + ako * 8);
            *reinterpret_cast<uint4*>(
                sWb + (aro << 7) + ((ako << 4) ^ ((aro & 7) << 4))) = v;
        }
        // ---- stage B: 64 px x 64 ch shifted-row load (bf16, coalesced) ----
        {
            const int k  = kc >> 2;
            const int c0 = (kc & 3) << 6;
            const int yy = h + k / 3 - 1;
            const int xx = w + (k % 3) - 1;
            const bool ok = ((unsigned)yy < HH_) & ((unsigned)xx < WW_);
            uint4 q0 = make_uint4(0u, 0u, 0u, 0u);
            uint4 q1 = make_uint4(0u, 0u, 0u, 0u);
            if (ok) {
                const uint4* src = reinterpret_cast<const uint4*>(
                    xtb + (size_t)(yy * WW_ + xx) * CHI_ + c0 + cg * 16);
                q0 = src[0];
                q1 = src[1];
            }
            const int u0 = cg << 1;
            *reinterpret_cast<uint4*>(
                sBb + (pxl << 7) + ((u0 << 4) ^ ((pxl & 7) << 4))) = q0;
            *reinterpret_cast<uint4*>(
                sBb + (pxl << 7) + (((u0 + 1) << 4) ^ ((pxl & 7) << 4))) = q1;
        }
        __syncthreads();
        // ---- MFMA: 2 K-steps; A = 2 oc-tiles, B = wave's pixel quarter ----
#pragma unroll
        for (int ks = 0; ks < 2; ks++) {
            short8 a0, a1, b0;
            {
                int r = l15;
                a0 = *reinterpret_cast<const short8*>(
                    sWb + (r << 7) + (((ks << 6) + (quad << 4)) ^ ((r & 7) << 4)));
                r = 16 + l15;
                a1 = *reinterpret_cast<const short8*>(
                    sWb + (r << 7) + (((ks << 6) + (quad << 4)) ^ ((r & 7) << 4)));
                r = wave * 16 + l15;
                b0 = *reinterpret_cast<const short8*>(
                    sBb + (r << 7) + (((ks << 6) + (quad << 4)) ^ ((r & 7) << 4)));
            }
            acc[0] = __builtin_amdgcn_mfma_f32_16x16x32_bf16(a0, b0, acc[0], 0, 0, 0);
            acc[1] = __builtin_amdgcn_mfma_f32_16x16x32_bf16(a1, b0, acc[1], 0, 0, 0);
        }
    }

    // epilogue: C/D layout col=lane&15 (pixel), row=quad*4+r (oc)
#pragma unroll
    for (int mt = 0; mt < 2; mt++) {
#pragma unroll
        for (int r = 0; r < 4; r++) {
            int oc = mt * 16 + quad * 4 + r;
            if (oc < 27) {
                int pix = p0 + wave * 16 + l15;
                om[((size_t)b * 27 + oc) * HW_ + pix] = acc[mt][r] + bo[oc];
            }
        }
    }
}

// ---------------------------------------------------------------------------
// Kernel 2: fused channels-last gather + bf16 MFMA GEMM (px-split).
//   R15: A-stage via global_load_lds (dest linear, source inverse-swizzled;
//   LDS image identical to R12's XOR layout). Rest = R12-measured.
// ---------------------------------------------------------------------------
__global__ __launch_bounds__(256, 4) void deform_fused(
    const float* __restrict__ xt, const float* __restrict__ om,
    const unsigned short* __restrict__ wb, const float* __restrict__ bconv,
    float* __restrict__ outb)
{
    __shared__ __align__(16) unsigned short sA[CHO_ * 64];   // 32768 B (swizzled)
    __shared__ __align__(16) unsigned short sB[32 * 64];     //  4096 B (swizzled)
    __shared__ float s_py[KK_ * 32], s_px[KK_ * 32], s_mask[KK_ * 32]; // 3456 B

    const int t = threadIdx.x;
    const int bid = blockIdx.x;
    const int u   = (bid & 7) * 144 + (bid >> 3);    // [0,1152)
    const int pixtile = u % 288;
    const int b       = u / 288;
    const int p0 = pixtile * 32;

    for (int e = t; e < KK_ * 32; e += 256) {
        int k = e >> 5, i = e & 31;
        int p = p0 + i;
        int h = p / WW_, w = p % WW_;
        const float* omb = om + ((size_t)b * 27) * HW_ + p;
        float dy = omb[(2 * k) * HW_];
        float dx = omb[(2 * k + 1) * HW_];
        float m  = omb[(18 + k) * HW_];
        s_py[e]   = dy + (float)(h + k / 3 - 1);
        s_px[e]   = dx + (float)(w + (k % 3) - 1);
        s_mask[e] = 1.f / (1.f + __expf(-m));
    }

    const int lane = t & 63, wave = t >> 6;
    const int quad = lane >> 4, l15 = lane & 15;
    const int pxl  = t >> 3;           // gather role: pixel 0..31
    const int cg   = t & 7;            // gather role: 8-ch group
    // A-stage (global_load_lds): lane covers row ocl = base8*8 + (lane>>3),
    // source column XOR (lane&7)^(lane>>3) — ocl&7 == lane>>3 for all iters.
    const int lane8  = lane >> 3;                       // 0..7
    const int srcxor = ((lane & 7) ^ lane8) << 3;       // in shorts

    f32x4 acc[4][2];
#pragma unroll
    for (int m = 0; m < 4; m++)
#pragma unroll
        for (int n = 0; n < 2; n++)
            acc[m][n] = (f32x4){0.f, 0.f, 0.f, 0.f};

    const float* xtb = xt + (size_t)b * HW_ * CHI_;
    char* sAb = (char*)sA;
    char* sBb = (char*)sB;

    __syncthreads();   // meta visible

    for (int kc = 0; kc < 36; kc++) {
        const int j0 = kc * 64;
        if (kc) __syncthreads();
        // ---- stage A (W'): 256 oc x 64 kk via 8x global_load_lds(16B) ----
#pragma unroll
        for (int n = 0; n < 8; n++) {
            int base8 = n * 4 + wave;                  // 8-row group 0..31
            int ocl   = base8 * 8 + lane8;
            const unsigned short* g = wb + (size_t)ocl * CK_ + j0 + srcxor;
            __builtin_amdgcn_global_load_lds(
                (const __attribute__((address_space(1))) unsigned int*)g,
                (__attribute__((address_space(3))) unsigned int*)(sAb + base8 * 1024),
                16, 0, 0);
        }
        // ---- stage B: gather 32 px x 64 ch for tap k (coalesced) ----
        {
            const int k  = kc >> 2;
            const int c0 = (kc & 3) << 6;
            const int e  = k * 32 + pxl;
            float py = s_py[e], pxx = s_px[e], msk = s_mask[e];
            float y0f = floorf(py), x0f = floorf(pxx);
            float ly = py - y0f, lx = pxx - x0f;
            int y0 = (int)y0f, x0 = (int)x0f;
            float vy0 = ((unsigned)y0       < HH_) ? 1.f : 0.f;
            float vy1 = ((unsigned)(y0 + 1) < HH_) ? 1.f : 0.f;
            float vx0 = ((unsigned)x0       < WW_) ? 1.f : 0.f;
            float vx1 = ((unsigned)(x0 + 1) < WW_) ? 1.f : 0.f;
            int yc0 = min(max(y0, 0), HH_ - 1), yc1 = min(max(y0 + 1, 0), HH_ - 1);
            int xc0 = min(max(x0, 0), WW_ - 1), xc1 = min(max(x0 + 1, 0), WW_ - 1);
            float wy0 = 1.f - ly, wx0 = 1.f - lx;
            float w00 = wy0 * wx0 * vy0 * vx0 * msk;
            float w01 = wy0 * lx  * vy0 * vx1 * msk;
            float w10 = ly  * wx0 * vy1 * vx0 * msk;
            float w11 = ly  * lx  * vy1 * vx1 * msk;
            const float* base = xtb + c0 + cg * 8;
            const float4* r00 = reinterpret_cast<const float4*>(
                base + (size_t)(yc0 * WW_ + xc0) * CHI_);
            const float4* r01 = reinterpret_cast<const float4*>(
                base + (size_t)(yc0 * WW_ + xc1) * CHI_);
            const float4* r10 = reinterpret_cast<const float4*>(
                base + (size_t)(yc1 * WW_ + xc0) * CHI_);
            const float4* r11 = reinterpret_cast<const float4*>(
                base + (size_t)(yc1 * WW_ + xc1) * CHI_);
            union { unsigned short s[8]; uint4 q; } pk;
#pragma unroll
            for (int i = 0; i < 2; i++) {
                float4 fa = r00[i], fb = r01[i], fc = r10[i], fd = r11[i];
                pk.s[i * 4 + 0] = f2bf(fa.x * w00 + fb.x * w01 + fc.x * w10 + fd.x * w11);
                pk.s[i * 4 + 1] = f2bf(fa.y * w00 + fb.y * w01 + fc.y * w10 + fd.y * w11);
                pk.s[i * 4 + 2] = f2bf(fa.z * w00 + fb.z * w01 + fc.z * w10 + fd.z * w11);
                pk.s[i * 4 + 3] = f2bf(fa.w * w00 + fb.w * w01 + fc.w * w10 + fd.w * w11);
            }
            *reinterpret_cast<uint4*>(
                sBb + (pxl << 7) + ((cg << 4) ^ ((pxl & 7) << 4))) = pk.q;
        }
        __syncthreads();
#pragma unroll
        for (int ks = 0; ks < 2; ks++) {
            short8 afr[4], bfr[2];
#pragma unroll
            for (int m = 0; m < 4; m++) {
                int r = wave * 64 + m * 16 + l15;
                afr[m] = *reinterpret_cast<const short8*>(
                    sAb + (r << 7) + (((ks << 6) + (quad << 4)) ^ ((r & 7) << 4)));
            }
#pragma unroll
            for (int n = 0; n < 2; n++) {
                int r = n * 16 + l15;
                bfr[n] = *reinterpret_cast<const short8*>(
                    sBb + (r << 7) + (((ks << 6) + (quad << 4)) ^ ((r & 7) << 4)));
            }
#pragma unroll
            for (int m = 0; m < 4; m++)
#pragma unroll
                for (int n = 0; n < 2; n++)
                    acc[m][n] = __builtin_amdgcn_mfma_f32_16x16x32_bf16(
                        afr[m], bfr[n], acc[m][n], 0, 0, 0);
        }
    }

#pragma unroll
    for (int m = 0; m < 4; m++) {
#pragma unroll
        for (int n = 0; n < 2; n++) {
#pragma unroll
            for (int r = 0; r < 4; r++) {
                int oc  = wave * 64 + m * 16 + quad * 4 + r;
                int pix = p0 + n * 16 + l15;
                outb[((size_t)b * CHO_ + oc) * HW_ + pix] = acc[m][n][r] + bconv[oc];
            }
        }
    }
}

// ---------------------------------------------------------------------------
// Kernel 3a: BN partial stats. 2048 blocks = channel x 8 slices, float4 loads.
// ---------------------------------------------------------------------------
__global__ __launch_bounds__(256) void bn_stats_part(
    const float* __restrict__ outb, float* __restrict__ part)
{
    const int bid = blockIdx.x;            // 2048
    const int o = bid >> 3, sl = bid & 7;
    const int t = threadIdx.x;
    float s = 0.f, s2 = 0.f;
    for (int b = 0; b < BN_; b++) {
        const float4* base = reinterpret_cast<const float4*>(
            outb + ((size_t)b * CHO_ + o) * HW_ + sl * 1152);
        for (int i = t; i < 288; i += 256) {     // 288 float4 = 1152 floats
            float4 v = base[i];
            s  += v.x + v.y + v.z + v.w;
            s2 += v.x * v.x + v.y * v.y + v.z * v.z + v.w * v.w;
        }
    }
#pragma unroll
    for (int off = 32; off > 0; off >>= 1) {
        s  += __shfl_down(s,  off, 64);
        s2 += __shfl_down(s2, off, 64);
    }
    __shared__ float rs[4], rs2[4];
    int lane = t & 63, wv = t >> 6;
    if (lane == 0) { rs[wv] = s; rs2[wv] = s2; }
    __syncthreads();
    if (t == 0) {
        part[o * 8 + sl]                = rs[0] + rs[1] + rs[2] + rs[3];
        part[CHO_ * 8 + o * 8 + sl]     = rs2[0] + rs2[1] + rs2[2] + rs2[3];
    }
}

// ---------------------------------------------------------------------------
// Kernel 3b: deterministic reduce of 8 partials per channel.
// ---------------------------------------------------------------------------
__global__ __launch_bounds__(256) void bn_reduce(
    const float* __restrict__ part, float* __restrict__ stats)
{
    int o = threadIdx.x;                   // one block of 256
    float s = 0.f, s2 = 0.f;
#pragma unroll
    for (int i = 0; i < 8; i++) {
        s  += part[o * 8 + i];
        s2 += part[CHO_ * 8 + o * 8 + i];
    }
    stats[o]        = s;
    stats[CHO_ + o] = s2;
}

// ---------------------------------------------------------------------------
// Kernel 4: BN apply + ReLU, f32 out (32-bit index math)
// ---------------------------------------------------------------------------
__global__ __launch_bounds__(256) void bn_apply(
    const float* __restrict__ outb, const float* __restrict__ stats,
    const float* __restrict__ gamma, const float* __restrict__ beta,
    float* __restrict__ y)
{
    unsigned idx = blockIdx.x * 256 + threadIdx.x;    // < 2359296
    unsigned o = (idx / 2304u) & 255u;                // (idx*4/HW_) % CHO_
    size_t i0 = (size_t)idx * 4;
    float4 v = *reinterpret_cast<const float4*>(outb + i0);
    const float invN = 1.f / (float)NRED_;
    float mu  = stats[o] * invN;
    float var = stats[CHO_ + o] * invN - mu * mu;
    float inv = rsqrtf(var + BN_EPS_);
    float sc = gamma[o] * inv;
    float sh = beta[o] - mu * sc;
    float4 r;
    r.x = fmaxf(v.x * sc + sh, 0.f);
    r.y = fmaxf(v.y * sc + sh, 0.f);
    r.z = fmaxf(v.z * sc + sh, 0.f);
    r.w = fmaxf(v.w * sc + sh, 0.f);
    *reinterpret_cast<float4*>(y + i0) = r;
}

// ---------------------------------------------------------------------------
extern "C" void kernel_launch(void* const* d_in, const int* in_sizes, int n_in,
                              void* d_out, int out_size, void* d_ws, size_t ws_size,
                              hipStream_t stream)
{
    const float* x   = (const float*)d_in[0];
    const float* wof = (const float*)d_in[1];
    const float* bof = (const float*)d_in[2];
    const float* wcv = (const float*)d_in[3];
    const float* bcv = (const float*)d_in[4];
    const float* gam = (const float*)d_in[5];
    const float* bet = (const float*)d_in[6];
    float* y = (float*)d_out;

    char* ws = (char*)d_ws;
    float*          om    = (float*)ws;                                   // 3.98 MB
    float*          outb  = (float*)(ws + (size_t)4 * 1024 * 1024);       // 36 MB
    float*          stats = (float*)(ws + (size_t)40 * 1024 * 1024);      // 2 KB
    unsigned short* wbf2  = (unsigned short*)(ws + (size_t)40 * 1024 * 1024 + 8192);            // 1.125 MB
    unsigned short* wob   = (unsigned short*)(ws + (size_t)40 * 1024 * 1024 + 8192 + 1179648);  // 121.5 KB
    float*          xt    = (float*)(ws + (size_t)44 * 1024 * 1024);      // 37.75 MB
    unsigned short* xt16  = (unsigned short*)(ws + (size_t)84 * 1024 * 1024); // 18.9 MB
    float*          part  = (float*)(ws + (size_t)104 * 1024 * 1024);     // 16 KB

    w2b_perm<<<(CHO_ * CK_) / 256, 256, 0, stream>>>(wcv, wbf2);  // 2304 blocks
    w2b_perm27<<<(27 * CK_) / 256, 256, 0, stream>>>(wof, wob);   // 243 blocks
    transpose_x<<<BN_ * 144 * 4, 256, 0, stream>>>(x, xt, xt16);  // 2304 blocks
    offset_nhwc<<<BN_ * 144, 256, 0, stream>>>(xt16, wob, bof, om); // 576 blocks
    deform_fused<<<BN_ * 2 * (HW_ / 64), 256, 0, stream>>>(xt, om, wbf2, bcv, outb);
    bn_stats_part<<<CHO_ * 8, 256, 0, stream>>>(outb, part);      // 2048 blocks
    bn_reduce<<<1, 256, 0, stream>>>(part, stats);
    bn_apply<<<(BN_ * CHO_ * HW_) / (4 * 256), 256, 0, stream>>>(outb, stats, gam, bet, y);
}

// Round 16
// 267.041 us; speedup vs baseline: 2.3128x; 1.0307x over previous
//
#include <hip/hip_runtime.h>
#include <math.h>

// Problem constants (DeformConv_68109591380935) — ALL TENSORS FLOAT32
#define BN_    4
#define CHI_   256
#define CHO_   256
#define HH_    96
#define WW_    96
#define HW_    (HH_*WW_)        // 9216
#define KK_    9
#define CK_    (CHI_*KK_)       // 2304
#define NRED_  (BN_*HW_)        // 36864 samples per BN channel
#define BN_EPS_ 1e-5f

// R16: offset_nhwc staging fully via global_load_lds (A: 32-row wob with
// zeroed rows 27..31; B: xt16 with OOB lanes redirected to the zero row).
// Linear LDS dest + inverse-swizzled per-lane source (R15-verified pattern).
// prep = w2b_perm + w2b_perm32 + transpose merged (one launch).
// deform_fused / bn_* = R15-measured controls, untouched.

typedef short short8 __attribute__((ext_vector_type(8)));
typedef float f32x4  __attribute__((ext_vector_type(4)));

// round-to-nearest-even f32 -> bf16 bit pattern
__device__ __forceinline__ unsigned short f2bf(float v) {
    union { float f; unsigned u; } c; c.f = v;
    unsigned lsb = (c.u >> 16) & 1u;
    c.u += 0x7fffu + lsb;
    return (unsigned short)(c.u >> 16);
}

// ---------------------------------------------------------------------------
// Kernel 0: merged prep.
//   blocks [0,2304):    wb2[o][k*256+c]   = bf16(w_conv[o][c*9+k])
//   blocks [2304,2592): wob32[o][k*256+c] = o<27 ? bf16(w_off[o][c*9+k]) : 0
//   blocks [2592,4896): xt/xt16 NHWC transpose of x
// ---------------------------------------------------------------------------
__global__ __launch_bounds__(256) void prep(
    const float* __restrict__ wcv, const float* __restrict__ wof,
    const float* __restrict__ x,
    unsigned short* __restrict__ wb2, unsigned short* __restrict__ wob32,
    float* __restrict__ xt, unsigned short* __restrict__ xt16)
{
    __shared__ float tile[64][65];
    const int t = threadIdx.x;
    const int bid = blockIdx.x;

    if (bid < 2304) {
        int idx = bid * 256 + t;                  // o*2304 + k*256 + c
        int o  = idx / CK_;
        int kk = idx - o * CK_;
        int k  = kk >> 8;
        int c  = kk & 255;
        wb2[idx] = f2bf(wcv[o * CK_ + c * KK_ + k]);
        return;
    }
    if (bid < 2592) {
        int idx = (bid - 2304) * 256 + t;         // < 32*2304
        int o  = idx / CK_;
        int kk = idx - o * CK_;
        int k  = kk >> 8;
        int c  = kk & 255;
        wob32[idx] = (o < 27) ? f2bf(wof[o * CK_ + c * KK_ + k]) : (unsigned short)0;
        return;
    }
    {
        const int r  = bid - 2592;                // [0,2304)
        const int b  = r / 576;
        const int rr = r - b * 576;
        const int pt = rr >> 2, ct = rr & 3;
        const int p0 = pt * 64, c0 = ct * 64;

        const int px = t & 63, g = t >> 6;
#pragma unroll
        for (int i = 0; i < 16; i++) {
            int cr = g + i * 4;
            tile[cr][px] = x[((size_t)b * CHI_ + c0 + cr) * HW_ + p0 + px];
        }
        __syncthreads();
        const int c = t & 63;
#pragma unroll
        for (int i = 0; i < 16; i++) {
            int pr = g + i * 4;
            float v = tile[c][pr];
            size_t o = ((size_t)b * HW_ + p0 + pr) * CHI_ + c0 + c;
            xt[o]   = v;
            xt16[o] = f2bf(v);
        }
    }
}

// ---------------------------------------------------------------------------
// Kernel 1: offset conv as channels-last MFMA GEMM.
//   R16: A and B staged via global_load_lds(16B). Linear dest; source
//   carries the XOR ((lane&7)^(lane>>3)). OOB / zero rows read wob32 row 31
//   (zeros). MFMA + epilogue unchanged (same LDS image as R15).
// ---------------------------------------------------------------------------
__global__ __launch_bounds__(256) void offset_nhwc(
    const unsigned short* __restrict__ xt16, const unsigned short* __restrict__ wob,
    const float* __restrict__ bo, float* __restrict__ om)
{
    __shared__ __align__(16) unsigned short sW[32 * 64];   // 4096 B (swizzled)
    __shared__ __align__(16) unsigned short sB[64 * 64];   // 8192 B (swizzled)

    const int t = threadIdx.x;
    const int bid = blockIdx.x;
    const int u   = (bid & 7) * 72 + (bid >> 3);     // [0,576)
    const int pixtile = u % 144;
    const int b       = u / 144;
    const int p0 = pixtile * 64;

    const int lane = t & 63, wave = t >> 6;
    const int quad = lane >> 4, l15 = lane & 15;
    const int lane8  = lane >> 3;                    // 0..7
    const int srcxor = ((lane & 7) ^ lane8) << 3;    // in shorts

    // B-stage pixel coords (two pixels per lane: n=0,1)
    const int pA = p0 + wave * 16 + lane8;
    const int pB = pA + 8;
    const int hA = pA / WW_, wA = pA % WW_;
    const int hB = pB / WW_, wB = pB % WW_;

    f32x4 acc[2];
    acc[0] = (f32x4){0.f,0.f,0.f,0.f};
    acc[1] = (f32x4){0.f,0.f,0.f,0.f};

    const unsigned short* xtb = xt16 + (size_t)b * HW_ * CHI_;
    const unsigned short* zsrc = wob + (size_t)31 * CK_;   // zeroed row
    char* sWb = (char*)sW;
    char* sBb = (char*)sB;

    for (int kc = 0; kc < 36; kc++) {
        if (kc) __syncthreads();
        // ---- stage A: 32 oc x 64 kk, 1 gload_lds per wave (8 rows each)
        {
            const unsigned short* g =
                wob + (size_t)(wave * 8 + lane8) * CK_ + kc * 64 + srcxor;
            __builtin_amdgcn_global_load_lds(
                (const __attribute__((address_space(1))) unsigned int*)g,
                (__attribute__((address_space(3))) unsigned int*)(sWb + wave * 1024),
                16, 0, 0);
        }
        // ---- stage B: 64 px x 64 ch shifted-row, 2 gload_lds per wave ----
        {
            const int k  = kc >> 2;
            const int c0 = (kc & 3) << 6;
            const int dy = k / 3 - 1, dx = (k % 3) - 1;
            int yy = hA + dy, xx = wA + dx;
            const unsigned short* g0 =
                (((unsigned)yy < HH_) & ((unsigned)xx < WW_))
                ? xtb + (size_t)(yy * WW_ + xx) * CHI_ + c0 + srcxor : zsrc;
            __builtin_amdgcn_global_load_lds(
                (const __attribute__((address_space(1))) unsigned int*)g0,
                (__attribute__((address_space(3))) unsigned int*)(sBb + wave * 2048),
                16, 0, 0);
            yy = hB + dy; xx = wB + dx;
            const unsigned short* g1 =
                (((unsigned)yy < HH_) & ((unsigned)xx < WW_))
                ? xtb + (size_t)(yy * WW_ + xx) * CHI_ + c0 + srcxor : zsrc;
            __builtin_amdgcn_global_load_lds(
                (const __attribute__((address_space(1))) unsigned int*)g1,
                (__attribute__((address_space(3))) unsigned int*)(sBb + wave * 2048 + 1024),
                16, 0, 0);
        }
        __syncthreads();
        // ---- MFMA: 2 K-steps; A = 2 oc-tiles, B = wave's pixel quarter ----
#pragma unroll
        for (int ks = 0; ks < 2; ks++) {
            short8 a0, a1, b0;
            {
                int r = l15;
                a0 = *reinterpret_cast<const short8*>(
                    sWb + (r << 7) + (((ks << 6) + (quad << 4)) ^ ((r & 7) << 4)));
                r = 16 + l15;
                a1 = *reinterpret_cast<const short8*>(
                    sWb + (r << 7) + (((ks << 6) + (quad << 4)) ^ ((r & 7) << 4)));
                r = wave * 16 + l15;
                b0 = *reinterpret_cast<const short8*>(
                    sBb + (r << 7) + (((ks << 6) + (quad << 4)) ^ ((r & 7) << 4)));
            }
            acc[0] = __builtin_amdgcn_mfma_f32_16x16x32_bf16(a0, b0, acc[0], 0, 0, 0);
            acc[1] = __builtin_amdgcn_mfma_f32_16x16x32_bf16(a1, b0, acc[1], 0, 0, 0);
        }
    }

    // epilogue: C/D layout col=lane&15 (pixel), row=quad*4+r (oc)
#pragma unroll
    for (int mt = 0; mt < 2; mt++) {
#pragma unroll
        for (int r = 0; r < 4; r++) {
            int oc = mt * 16 + quad * 4 + r;
            if (oc < 27) {
                int pix = p0 + wave * 16 + l15;
                om[((size_t)b * 27 + oc) * HW_ + pix] = acc[mt][r] + bo[oc];
            }
        }
    }
}

// ---------------------------------------------------------------------------
// Kernel 2: fused channels-last gather + bf16 MFMA GEMM (px-split).
//   UNCHANGED from R15-measured (129 us).
// ---------------------------------------------------------------------------
__global__ __launch_bounds__(256, 4) void deform_fused(
    const float* __restrict__ xt, const float* __restrict__ om,
    const unsigned short* __restrict__ wb, const float* __restrict__ bconv,
    float* __restrict__ outb)
{
    __shared__ __align__(16) unsigned short sA[CHO_ * 64];   // 32768 B (swizzled)
    __shared__ __align__(16) unsigned short sB[32 * 64];     //  4096 B (swizzled)
    __shared__ float s_py[KK_ * 32], s_px[KK_ * 32], s_mask[KK_ * 32]; // 3456 B

    const int t = threadIdx.x;
    const int bid = blockIdx.x;
    const int u   = (bid & 7) * 144 + (bid >> 3);    // [0,1152)
    const int pixtile = u % 288;
    const int b       = u / 288;
    const int p0 = pixtile * 32;

    for (int e = t; e < KK_ * 32; e += 256) {
        int k = e >> 5, i = e & 31;
        int p = p0 + i;
        int h = p / WW_, w = p % WW_;
        const float* omb = om + ((size_t)b * 27) * HW_ + p;
        float dy = omb[(2 * k) * HW_];
        float dx = omb[(2 * k + 1) * HW_];
        float m  = omb[(18 + k) * HW_];
        s_py[e]   = dy + (float)(h + k / 3 - 1);
        s_px[e]   = dx + (float)(w + (k % 3) - 1);
        s_mask[e] = 1.f / (1.f + __expf(-m));
    }

    const int lane = t & 63, wave = t >> 6;
    const int quad = lane >> 4, l15 = lane & 15;
    const int pxl  = t >> 3;           // gather role: pixel 0..31
    const int cg   = t & 7;            // gather role: 8-ch group
    const int lane8  = lane >> 3;                       // 0..7
    const int srcxor = ((lane & 7) ^ lane8) << 3;       // in shorts

    f32x4 acc[4][2];
#pragma unroll
    for (int m = 0; m < 4; m++)
#pragma unroll
        for (int n = 0; n < 2; n++)
            acc[m][n] = (f32x4){0.f, 0.f, 0.f, 0.f};

    const float* xtb = xt + (size_t)b * HW_ * CHI_;
    char* sAb = (char*)sA;
    char* sBb = (char*)sB;

    __syncthreads();   // meta visible

    for (int kc = 0; kc < 36; kc++) {
        const int j0 = kc * 64;
        if (kc) __syncthreads();
        // ---- stage A (W'): 256 oc x 64 kk via 8x global_load_lds(16B) ----
#pragma unroll
        for (int n = 0; n < 8; n++) {
            int base8 = n * 4 + wave;                  // 8-row group 0..31
            int ocl   = base8 * 8 + lane8;
            const unsigned short* g = wb + (size_t)ocl * CK_ + j0 + srcxor;
            __builtin_amdgcn_global_load_lds(
                (const __attribute__((address_space(1))) unsigned int*)g,
                (__attribute__((address_space(3))) unsigned int*)(sAb + base8 * 1024),
                16, 0, 0);
        }
        // ---- stage B: gather 32 px x 64 ch for tap k (coalesced) ----
        {
            const int k  = kc >> 2;
            const int c0 = (kc & 3) << 6;
            const int e  = k * 32 + pxl;
            float py = s_py[e], pxx = s_px[e], msk = s_mask[e];
            float y0f = floorf(py), x0f = floorf(pxx);
            float ly = py - y0f, lx = pxx - x0f;
            int y0 = (int)y0f, x0 = (int)x0f;
            float vy0 = ((unsigned)y0       < HH_) ? 1.f : 0.f;
            float vy1 = ((unsigned)(y0 + 1) < HH_) ? 1.f : 0.f;
            float vx0 = ((unsigned)x0       < WW_) ? 1.f : 0.f;
            float vx1 = ((unsigned)(x0 + 1) < WW_) ? 1.f : 0.f;
            int yc0 = min(max(y0, 0), HH_ - 1), yc1 = min(max(y0 + 1, 0), HH_ - 1);
            int xc0 = min(max(x0, 0), WW_ - 1), xc1 = min(max(x0 + 1, 0), WW_ - 1);
            float wy0 = 1.f - ly, wx0 = 1.f - lx;
            float w00 = wy0 * wx0 * vy0 * vx0 * msk;
            float w01 = wy0 * lx  * vy0 * vx1 * msk;
            float w10 = ly  * wx0 * vy1 * vx0 * msk;
            float w11 = ly  * lx  * vy1 * vx1 * msk;
            const float* base = xtb + c0 + cg * 8;
            const float4* r00 = reinterpret_cast<const float4*>(
                base + (size_t)(yc0 * WW_ + xc0) * CHI_);
            const float4* r01 = reinterpret_cast<const float4*>(
                base + (size_t)(yc0 * WW_ + xc1) * CHI_);
            const float4* r10 = reinterpret_cast<const float4*>(
                base + (size_t)(yc1 * WW_ + xc0) * CHI_);
            const float4* r11 = reinterpret_cast<const float4*>(
                base + (size_t)(yc1 * WW_ + xc1) * CHI_);
            union { unsigned short s[8]; uint4 q; } pk;
#pragma unroll
            for (int i = 0; i < 2; i++) {
                float4 fa = r00[i], fb = r01[i], fc = r10[i], fd = r11[i];
                pk.s[i * 4 + 0] = f2bf(fa.x * w00 + fb.x * w01 + fc.x * w10 + fd.x * w11);
                pk.s[i * 4 + 1] = f2bf(fa.y * w00 + fb.y * w01 + fc.y * w10 + fd.y * w11);
                pk.s[i * 4 + 2] = f2bf(fa.z * w00 + fb.z * w01 + fc.z * w10 + fd.z * w11);
                pk.s[i * 4 + 3] = f2bf(fa.w * w00 + fb.w * w01 + fc.w * w10 + fd.w * w11);
            }
            *reinterpret_cast<uint4*>(
                sBb + (pxl << 7) + ((cg << 4) ^ ((pxl & 7) << 4))) = pk.q;
        }
        __syncthreads();
#pragma unroll
        for (int ks = 0; ks < 2; ks++) {
            short8 afr[4], bfr[2];
#pragma unroll
            for (int m = 0; m < 4; m++) {
                int r = wave * 64 + m * 16 + l15;
                afr[m] = *reinterpret_cast<const short8*>(
                    sAb + (r << 7) + (((ks << 6) + (quad << 4)) ^ ((r & 7) << 4)));
            }
#pragma unroll
            for (int n = 0; n < 2; n++) {
                int r = n * 16 + l15;
                bfr[n] = *reinterpret_cast<const short8*>(
                    sBb + (r << 7) + (((ks << 6) + (quad << 4)) ^ ((r & 7) << 4)));
            }
#pragma unroll
            for (int m = 0; m < 4; m++)
#pragma unroll
                for (int n = 0; n < 2; n++)
                    acc[m][n] = __builtin_amdgcn_mfma_f32_16x16x32_bf16(
                        afr[m], bfr[n], acc[m][n], 0, 0, 0);
        }
    }

#pragma unroll
    for (int m = 0; m < 4; m++) {
#pragma unroll
        for (int n = 0; n < 2; n++) {
#pragma unroll
            for (int r = 0; r < 4; r++) {
                int oc  = wave * 64 + m * 16 + quad * 4 + r;
                int pix = p0 + n * 16 + l15;
                outb[((size_t)b * CHO_ + oc) * HW_ + pix] = acc[m][n][r] + bconv[oc];
            }
        }
    }
}

// ---------------------------------------------------------------------------
// Kernel 3a: BN partial stats. 2048 blocks = channel x 8 slices, float4 loads.
// ---------------------------------------------------------------------------
__global__ __launch_bounds__(256) void bn_stats_part(
    const float* __restrict__ outb, float* __restrict__ part)
{
    const int bid = blockIdx.x;            // 2048
    const int o = bid >> 3, sl = bid & 7;
    const int t = threadIdx.x;
    float s = 0.f, s2 = 0.f;
    for (int b = 0; b < BN_; b++) {
        const float4* base = reinterpret_cast<const float4*>(
            outb + ((size_t)b * CHO_ + o) * HW_ + sl * 1152);
        for (int i = t; i < 288; i += 256) {     // 288 float4 = 1152 floats
            float4 v = base[i];
            s  += v.x + v.y + v.z + v.w;
            s2 += v.x * v.x + v.y * v.y + v.z * v.z + v.w * v.w;
        }
    }
#pragma unroll
    for (int off = 32; off > 0; off >>= 1) {
        s  += __shfl_down(s,  off, 64);
        s2 += __shfl_down(s2, off, 64);
    }
    __shared__ float rs[4], rs2[4];
    int lane = t & 63, wv = t >> 6;
    if (lane == 0) { rs[wv] = s; rs2[wv] = s2; }
    __syncthreads();
    if (t == 0) {
        part[o * 8 + sl]                = rs[0] + rs[1] + rs[2] + rs[3];
        part[CHO_ * 8 + o * 8 + sl]     = rs2[0] + rs2[1] + rs2[2] + rs2[3];
    }
}

// ---------------------------------------------------------------------------
// Kernel 3b: deterministic reduce of 8 partials per channel.
// ---------------------------------------------------------------------------
__global__ __launch_bounds__(256) void bn_reduce(
    const float* __restrict__ part, float* __restrict__ stats)
{
    int o = threadIdx.x;                   // one block of 256
    float s = 0.f, s2 = 0.f;
#pragma unroll
    for (int i = 0; i < 8; i++) {
        s  += part[o * 8 + i];
        s2 += part[CHO_ * 8 + o * 8 + i];
    }
    stats[o]        = s;
    stats[CHO_ + o] = s2;
}

// ---------------------------------------------------------------------------
// Kernel 4: BN apply + ReLU, f32 out (32-bit index math)
// ---------------------------------------------------------------------------
__global__ __launch_bounds__(256) void bn_apply(
    const float* __restrict__ outb, const float* __restrict__ stats,
    const float* __restrict__ gamma, const float* __restrict__ beta,
    float* __restrict__ y)
{
    unsigned idx = blockIdx.x * 256 + threadIdx.x;    // < 2359296
    unsigned o = (idx / 2304u) & 255u;                // (idx*4/HW_) % CHO_
    size_t i0 = (size_t)idx * 4;
    float4 v = *reinterpret_cast<const float4*>(outb + i0);
    const float invN = 1.f / (float)NRED_;
    float mu  = stats[o] * invN;
    float var = stats[CHO_ + o] * invN - mu * mu;
    float inv = rsqrtf(var + BN_EPS_);
    float sc = gamma[o] * inv;
    float sh = beta[o] - mu * sc;
    float4 r;
    r.x = fmaxf(v.x * sc + sh, 0.f);
    r.y = fmaxf(v.y * sc + sh, 0.f);
    r.z = fmaxf(v.z * sc + sh, 0.f);
    r.w = fmaxf(v.w * sc + sh, 0.f);
    *reinterpret_cast<float4*>(y + i0) = r;
}

// ---------------------------------------------------------------------------
extern "C" void kernel_launch(void* const* d_in, const int* in_sizes, int n_in,
                              void* d_out, int out_size, void* d_ws, size_t ws_size,
                              hipStream_t stream)
{
    const float* x   = (const float*)d_in[0];
    const float* wof = (const float*)d_in[1];
    const float* bof = (const float*)d_in[2];
    const float* wcv = (const float*)d_in[3];
    const float* bcv = (const float*)d_in[4];
    const float* gam = (const float*)d_in[5];
    const float* bet = (const float*)d_in[6];
    float* y = (float*)d_out;

    char* ws = (char*)d_ws;
    float*          om    = (float*)ws;                                   // 3.98 MB
    float*          outb  = (float*)(ws + (size_t)4 * 1024 * 1024);       // 36 MB
    float*          stats = (float*)(ws + (size_t)40 * 1024 * 1024);      // 2 KB
    unsigned short* wbf2  = (unsigned short*)(ws + (size_t)40 * 1024 * 1024 + 8192);            // 1.125 MB
    unsigned short* wob32 = (unsigned short*)(ws + (size_t)40 * 1024 * 1024 + 8192 + 1179648);  // 144 KB (32 rows)
    float*          xt    = (float*)(ws + (size_t)44 * 1024 * 1024);      // 37.75 MB
    unsigned short* xt16  = (unsigned short*)(ws + (size_t)84 * 1024 * 1024); // 18.9 MB
    float*          part  = (float*)(ws + (size_t)104 * 1024 * 1024);     // 16 KB

    prep<<<4896, 256, 0, stream>>>(wcv, wof, x, wbf2, wob32, xt, xt16);
    offset_nhwc<<<BN_ * 144, 256, 0, stream>>>(xt16, wob32, bof, om); // 576 blocks
    deform_fused<<<BN_ * 2 * (HW_ / 64), 256, 0, stream>>>(xt, om, wbf2, bcv, outb);
    bn_stats_part<<<CHO_ * 8, 256, 0, stream>>>(outb, part);      // 2048 blocks
    bn_reduce<<<1, 256, 0, stream>>>(part, stats);
    bn_apply<<<(BN_ * CHO_ * HW_) / (4 * 256), 256, 0, stream>>>(outb, stats, gam, bet, y);
}